// Round 4
// baseline (298.272 us; speedup 1.0000x reference)
//
#include <hip/hip_runtime.h>
#include <math.h>

typedef __attribute__((ext_vector_type(8))) short bf16x8;
typedef __attribute__((ext_vector_type(4))) float f32x4;
typedef __attribute__((ext_vector_type(16))) float f32x16;

#define HID 2048
#define SEQ 2048
#define NH  16
#define DH  128
#define QK_SCALE 0.02209708691207961f  // 1/sqrt(2048)

__device__ __forceinline__ ushort f2bf(float f) {
  union { float f; unsigned u; } v; v.f = f;
  unsigned r = v.u + 0x7fffu + ((v.u >> 16) & 1u);
  return (ushort)(r >> 16);
}

// async global->LDS, 16B per lane. lds ptr must be wave-uniform; HW adds lane*16.
__device__ __forceinline__ void gload16(const ushort* g, ushort* l) {
  __builtin_amdgcn_global_load_lds((const __attribute__((address_space(1))) void*)g,
                                   (__attribute__((address_space(3))) void*)l,
                                   16, 0, 0);
}

#define VMCNT(n) asm volatile("s_waitcnt vmcnt(" #n ")" ::: "memory")
#define LGKM0()  do { asm volatile("s_waitcnt lgkmcnt(0)" ::: "memory"); \
                      __builtin_amdgcn_sched_barrier(0); } while (0)
#define BAR()    __builtin_amdgcn_s_barrier()

// ---------- transpose fp32 [2048][2048] -> bf16 [2048][2048] (Wt[n][k] = W[k][n]) ----------
__global__ __launch_bounds__(256) void k_transpose(const float* __restrict__ W,
                                                   ushort* __restrict__ Wt) {
  __shared__ float t[32][33];
  int n0 = blockIdx.x * 32, k0 = blockIdx.y * 32;
  int tx = threadIdx.x, ty = threadIdx.y;
  for (int i = ty; i < 32; i += 8)
    t[i][tx] = W[(size_t)(k0 + i) * HID + n0 + tx];
  __syncthreads();
  for (int i = ty; i < 32; i += 8)
    Wt[(size_t)(n0 + i) * HID + k0 + tx] = f2bf(t[tx][i]);
}

// ---------- RMSNorm: x fp32 [4096][2048] -> xn bf16 ----------
__global__ __launch_bounds__(256) void k_rmsnorm(const float* __restrict__ x,
                                                 const float* __restrict__ w,
                                                 ushort* __restrict__ xn) {
  int row = blockIdx.x;
  const float* xr = x + (size_t)row * HID;
  int base = threadIdx.x * 8;
  float4 a = *(const float4*)(xr + base);
  float4 c = *(const float4*)(xr + base + 4);
  float ss = a.x*a.x + a.y*a.y + a.z*a.z + a.w*a.w
           + c.x*c.x + c.y*c.y + c.z*c.z + c.w*c.w;
  #pragma unroll
  for (int off = 32; off > 0; off >>= 1) ss += __shfl_xor(ss, off);
  __shared__ float red[4];
  if ((threadIdx.x & 63) == 0) red[threadIdx.x >> 6] = ss;
  __syncthreads();
  float tot = red[0] + red[1] + red[2] + red[3];
  float sc = rsqrtf(tot * (1.0f / HID) + 1e-5f);
  float4 wa = *(const float4*)(w + base);
  float4 wc = *(const float4*)(w + base + 4);
  ushort h[8];
  h[0] = f2bf(a.x * sc * wa.x); h[1] = f2bf(a.y * sc * wa.y);
  h[2] = f2bf(a.z * sc * wa.z); h[3] = f2bf(a.w * sc * wa.w);
  h[4] = f2bf(c.x * sc * wc.x); h[5] = f2bf(c.y * sc * wc.y);
  h[6] = f2bf(c.z * sc * wc.z); h[7] = f2bf(c.w * sc * wc.w);
  int4 pk;
  pk.x = h[0] | ((int)h[1] << 16);
  pk.y = h[2] | ((int)h[3] << 16);
  pk.z = h[4] | ((int)h[5] << 16);
  pk.w = h[6] | ((int)h[7] << 16);
  *(int4*)&xn[(size_t)row * HID + base] = pk;
}

// ---------- GEMM v3: 8-phase interleaved pipeline (T2+T3+T4+T5) ----------
// C[M][N] = A[M][K](bf16) * Bt[N][K](bf16)^T.  BM=256, BN=128, 8 waves (4Mx2N,
// per-wave 64x64, acc[4][4]).  BK=64 split in 2 k-half regions.
// LDS 96KB: A regions [2buf][2kh][256][32] (16KB ea), B [2buf][2kh][128][32] (8KB ea).
// Phase p of K-tile t: kk=p>>1, ih=p&1; even phase reads all frags for kk
// (8x ds_read_b128), stages 1 region of a future tile, lgkm(0)+MFMA(i=0,1);
// odd phase stages 1 region, MFMA(i=2,3), then vmcnt(6) before its barrier.
// Region staged at phase P is last-read at phase P-2 (WAR safe, skew<1 phase);
// vmcnt(6) at odd-phase end completes exactly the regions phases P+1..P+2 read.
// Swizzle: 16B chunk cp = ck ^ (row&3), both sides (stage source pre-swizzled,
// ds_read applies same XOR) -> worst 2-way conflict (free).
template <int MODE>
__global__ __launch_bounds__(512, 2) void k_gemm3(const ushort* __restrict__ A,
                                                  const ushort* __restrict__ Bt,
                                                  ushort* __restrict__ obf,
                                                  ushort* __restrict__ vt,
                                                  float* __restrict__ ofl,
                                                  const float* __restrict__ resid) {
  constexpr int K = 2048;                           // 32 K-tiles of 64
  constexpr int NBN = (MODE == 0) ? 48 : 16;
  constexpr int QX = ((MODE == 0) ? 768 : 256) / 8;
  __shared__ ushort lds[49152];
  const int tid = threadIdx.x;
  const int lane = tid & 63, w = tid >> 6;
  const int wm = w >> 1, wn = w & 1;
  const int g = lane >> 4, l15 = lane & 15;
  const int swz = (blockIdx.x & 7) * QX + (blockIdx.x >> 3);
  const int bm = swz / NBN, bn = swz % NBN;

  f32x4 acc[4][4];
  #pragma unroll
  for (int i = 0; i < 4; ++i)
    #pragma unroll
    for (int j = 0; j < 4; ++j) acc[i][j] = f32x4{0.f, 0.f, 0.f, 0.f};
  bf16x8 aF[4], bF[4];

  auto dsA = [&](int buf, int kk) {
    const ushort* base = lds + (buf * 2 + kk) * 8192;
    #pragma unroll
    for (int i = 0; i < 4; ++i) {
      int row = wm * 64 + i * 16 + l15;
      aF[i] = *(const bf16x8*)&base[row * 32 + ((g ^ (row & 3)) * 8)];
    }
  };
  auto dsB = [&](int buf, int kk) {
    const ushort* base = lds + 32768 + (buf * 2 + kk) * 4096;
    #pragma unroll
    for (int j = 0; j < 4; ++j) {
      int row = wn * 64 + j * 16 + l15;
      bF[j] = *(const bf16x8*)&base[row * 32 + ((g ^ (row & 3)) * 8)];
    }
  };
  auto stA = [&](int buf, int kk, int t2) {   // 2 loads/thread, 16KB region
    ushort* base = lds + (buf * 2 + kk) * 8192;
    #pragma unroll
    for (int L = 0; L < 2; ++L) {
      int r = (L * 8 + w) * 16 + (lane >> 2);
      int ck = (lane & 3) ^ (r & 3);
      gload16(&A[(size_t)(bm * 256 + r) * K + t2 * 64 + kk * 32 + ck * 8],
              base + (L * 8 + w) * 512);
    }
  };
  auto stB = [&](int buf, int kk, int t2) {   // 1 load/thread, 8KB region
    ushort* base = lds + 32768 + (buf * 2 + kk) * 4096;
    int r = w * 16 + (lane >> 2);
    int ck = (lane & 3) ^ (r & 3);
    gload16(&Bt[(size_t)(bn * 128 + r) * K + t2 * 64 + kk * 32 + ck * 8],
            base + w * 512);
  };
  auto MF = [&](int ih) {
    __builtin_amdgcn_s_setprio(1);
    #pragma unroll
    for (int i = 0; i < 2; ++i)
      #pragma unroll
      for (int j = 0; j < 4; ++j)
        acc[ih * 2 + i][j] =
            __builtin_amdgcn_mfma_f32_16x16x32_bf16(aF[ih * 2 + i], bF[j],
                                                    acc[ih * 2 + i][j], 0, 0, 0);
    __builtin_amdgcn_s_setprio(0);
  };

  // prologue: tile0 all 4 regions + tile1 k0 regions = 9 loads; need first 3.
  stA(0, 0, 0); stB(0, 0, 0); stA(0, 1, 0); stB(0, 1, 0); stA(1, 0, 1); stB(1, 0, 1);
  VMCNT(6); BAR();

  #pragma unroll 1
  for (int t = 0; t < 30; t += 2) {
    // tile t (buf0)
    dsA(0, 0); dsB(0, 0); stA(1, 1, t + 1); LGKM0(); MF(0); BAR();
    stB(1, 1, t + 1); MF(1); VMCNT(6); BAR();
    dsA(0, 1); dsB(0, 1); stA(0, 0, t + 2); LGKM0(); MF(0); BAR();
    stB(0, 0, t + 2); MF(1); VMCNT(6); BAR();
    // tile t+1 (buf1)
    dsA(1, 0); dsB(1, 0); stA(0, 1, t + 2); LGKM0(); MF(0); BAR();
    stB(0, 1, t + 2); MF(1); VMCNT(6); BAR();
    dsA(1, 1); dsB(1, 1); stA(1, 0, t + 3); LGKM0(); MF(0); BAR();
    stB(1, 0, t + 3); MF(1); VMCNT(6); BAR();
  }
  // tail: tile 30 (buf0) — stage only tile31 k1; drain 6 -> 3 -> 0
  dsA(0, 0); dsB(0, 0); stA(1, 1, 31); LGKM0(); MF(0); BAR();
  stB(1, 1, 31); MF(1); VMCNT(6); BAR();
  dsA(0, 1); dsB(0, 1); LGKM0(); MF(0); BAR();
  MF(1); VMCNT(3); BAR();
  // tile 31 (buf1)
  dsA(1, 0); dsB(1, 0); LGKM0(); MF(0); BAR();
  MF(1); VMCNT(0); BAR();
  dsA(1, 1); dsB(1, 1); LGKM0(); MF(0); BAR();
  MF(1);

  // C/D layout: col = lane&15, row = (lane>>4)*4 + r
  int rbase = bm * 256 + wm * 64 + g * 4;
  int cbase = bn * 128 + wn * 64 + l15;
  #pragma unroll
  for (int i = 0; i < 4; ++i) {
    #pragma unroll
    for (int j = 0; j < 4; ++j) {
      int col = cbase + j * 16;
      #pragma unroll
      for (int r = 0; r < 4; ++r) {
        int row = rbase + i * 16 + r;
        float v = acc[i][j][r];
        if (MODE == 0) {
          ushort hv = f2bf(v);
          if (col < 4096) {
            obf[(size_t)row * 4096 + col] = hv;
          } else {
            int nv = col - 4096;
            int h = nv >> 7, d = nv & 127;
            int b = row >> 11, s = row & 2047;
            vt[(size_t)((b * NH + h) * DH + d) * SEQ + s] = hv;
          }
        } else {
          ofl[(size_t)row * HID + col] = v + resid[(size_t)row * HID + col];
        }
      }
    }
  }
}

// ---------- flash attention v2: 4 waves x QBLK=32, KVBLK=64, 32x32x16 MFMA ----------
__global__ __launch_bounds__(256, 2) void k_attn2(const ushort* __restrict__ qk,
                                                  const ushort* __restrict__ vt,
                                                  ushort* __restrict__ aout) {
  __shared__ ushort sK[64 * 128];
  __shared__ ushort sV[128 * 64];
  const int tid = threadIdx.x;
  const int lane = tid & 63, w = tid >> 6;
  const int h2 = lane >> 5;          // half of wave
  const int l31 = lane & 31;
  const int bid = blockIdx.x;
  const int t = bid >> 3;
  const int bh = (bid & 7) + 8 * (t >> 4);
  const int qblk = 15 - (t & 15);
  const int b = bh >> 4, hh = bh & 15;
  const int q0w = qblk * 128 + w * 32;   // this wave's 32 q rows

  bf16x8 qf[8];
  {
    const ushort* qbase = qk + (size_t)(b * SEQ + q0w + l31) * 4096 + hh * DH;
    #pragma unroll
    for (int kk = 0; kk < 8; ++kk) qf[kk] = *(const bf16x8*)&qbase[kk * 16 + h2 * 8];
  }

  f32x16 accO[4];
  #pragma unroll
  for (int i = 0; i < 4; ++i)
    #pragma unroll
    for (int r = 0; r < 16; ++r) accO[i][r] = 0.f;
  float m_r = -1e30f, l_r = 0.f;

  const int ntile = 2 * qblk + 2;
  for (int tt = 0; tt < ntile; ++tt) {
    const int t0 = tt * 64;
    #pragma unroll
    for (int c = 0; c < 4; ++c) {
      int id = (w * 4 + c) * 64 + lane;
      int kr = id >> 4, ck = id & 15;   // sK: 256B rows, 16 chunks
      gload16(qk + (size_t)(b * SEQ + t0 + kr) * 4096 + 2048 + hh * DH + ((ck ^ (kr & 7)) * 8),
              ((ushort*)sK) + (size_t)(w * 4 + c) * 512);
      int dr = id >> 3, cv = id & 7;    // sV: 128B rows, 8 chunks
      gload16(vt + (size_t)(bh * DH + dr) * SEQ + t0 + ((cv ^ (dr & 7)) * 8),
              ((ushort*)sV) + (size_t)(w * 4 + c) * 512);
    }
    __syncthreads();

    if (t0 <= q0w + 31) {
      f32x16 accS[2];
      #pragma unroll
      for (int i = 0; i < 2; ++i)
        #pragma unroll
        for (int r = 0; r < 16; ++r) accS[i][r] = 0.f;
      #pragma unroll
      for (int kt = 0; kt < 2; ++kt) {
        const int row = kt * 32 + l31;
        #pragma unroll
        for (int kk = 0; kk < 8; ++kk) {
          const int cp = (kk * 2 + h2) ^ (lane & 7);
          bf16x8 kf = *(const bf16x8*)&sK[row * 128 + cp * 8];
          accS[kt] = __builtin_amdgcn_mfma_f32_32x32x16_bf16(kf, qf[kk], accS[kt], 0, 0, 0);
        }
      }
      const int qa = q0w + l31;
      float pmax = -INFINITY;
      if (t0 + 63 <= q0w) {
        #pragma unroll
        for (int kt = 0; kt < 2; ++kt)
          #pragma unroll
          for (int r = 0; r < 16; ++r) {
            float s = accS[kt][r] * QK_SCALE;
            accS[kt][r] = s;
            pmax = fmaxf(pmax, s);
          }
      } else {
        #pragma unroll
        for (int kt = 0; kt < 2; ++kt)
          #pragma unroll
          for (int r = 0; r < 16; ++r) {
            int ka = t0 + kt * 32 + (r & 3) + 8 * (r >> 2) + 4 * h2;
            float s = (ka <= qa) ? accS[kt][r] * QK_SCALE : -INFINITY;
            accS[kt][r] = s;
            pmax = fmaxf(pmax, s);
          }
      }
      pmax = fmaxf(pmax, __shfl_xor(pmax, 32));
      if (__any(pmax > m_r + 8.f)) {
        float mn = fmaxf(m_r, pmax);
        float al = __expf(m_r - mn);
        m_r = mn;
        l_r *= al;
        #pragma unroll
        for (int r = 0; r < 16; ++r) {
          float ar = __shfl(al, (r & 3) + 8 * (r >> 2) + 4 * h2);
          #pragma unroll
          for (int ds = 0; ds < 4; ++ds) accO[ds][r] *= ar;
        }
      }
      float rs = 0.f;
      #pragma unroll
      for (int kt = 0; kt < 2; ++kt)
        #pragma unroll
        for (int r = 0; r < 16; ++r) {
          float p = __expf(accS[kt][r] - m_r);
          rs += p;
          accS[kt][r] = p;
        }
      rs += __shfl_xor(rs, 32);
      l_r += rs;
      uint W[2][4][2];
      #pragma unroll
      for (int kt = 0; kt < 2; ++kt)
        #pragma unroll
        for (int bq = 0; bq < 4; ++bq)
          #pragma unroll
          for (int w2 = 0; w2 < 2; ++w2) {
            uint u0 = __float_as_uint(accS[kt][bq * 4 + w2 * 2]);
            uint u1 = __float_as_uint(accS[kt][bq * 4 + w2 * 2 + 1]);
            W[kt][bq][w2] = (u0 >> 16) | (u1 & 0xffff0000u);
          }
      #pragma unroll
      for (int kc = 0; kc < 4; ++kc) {
        const int kt = kc >> 1, pq = kc & 1;
        uint X0 = W[kt][2 * pq][0],     X1 = W[kt][2 * pq][1];
        uint Y0 = W[kt][2 * pq + 1][0], Y1 = W[kt][2 * pq + 1][1];
        uint sx0 = (uint)__shfl_xor((int)X0, 32);
        uint sx1 = (uint)__shfl_xor((int)X1, 32);
        uint sy0 = (uint)__shfl_xor((int)Y0, 32);
        uint sy1 = (uint)__shfl_xor((int)Y1, 32);
        union { uint u[4]; bf16x8 v; } pu;
        pu.u[0] = h2 ? sy0 : X0;
        pu.u[1] = h2 ? sy1 : X1;
        pu.u[2] = h2 ? Y0 : sx0;
        pu.u[3] = h2 ? Y1 : sx1;
        #pragma unroll
        for (int ds = 0; ds < 4; ++ds) {
          const int dr = ds * 32 + l31;
          const int cp = (kc * 2 + h2) ^ (lane & 7);
          bf16x8 vf = *(const bf16x8*)&sV[dr * 64 + cp * 8];
          accO[ds] = __builtin_amdgcn_mfma_f32_32x32x16_bf16(pu.v, vf, accO[ds], 0, 0, 0);
        }
      }
    }
    __syncthreads();
  }

  float linv = 1.f / l_r;
  #pragma unroll
  for (int r = 0; r < 16; ++r) {
    int qrel = (r & 3) + 8 * (r >> 2) + 4 * h2;
    float li = __shfl(linv, qrel);
    #pragma unroll
    for (int ds = 0; ds < 4; ++ds) {
      aout[(size_t)(b * SEQ + q0w + qrel) * HID + hh * DH + ds * 32 + l31] =
          f2bf(accO[ds][r] * li);
    }
  }
}

extern "C" void kernel_launch(void* const* d_in, const int* in_sizes, int n_in,
                              void* d_out, int out_size, void* d_ws, size_t ws_size,
                              hipStream_t stream) {
  const float* x     = (const float*)d_in[0];
  const float* rms_w = (const float*)d_in[1];
  const float* Wq    = (const float*)d_in[2];
  const float* Wk    = (const float*)d_in[3];
  const float* Wv    = (const float*)d_in[4];
  const float* Wo    = (const float*)d_in[5];
  float* out = (float*)d_out;

  char* ws = (char*)d_ws;
  ushort* WqkvT = (ushort*)ws; ws += (size_t)6144 * 2048 * 2;  // [6144][2048]
  ushort* WoT   = (ushort*)ws; ws += (size_t)2048 * 2048 * 2;  // [2048][2048]
  ushort* xn    = (ushort*)ws; ws += (size_t)4096 * 2048 * 2;  // [4096][2048]
  ushort* qkbuf = (ushort*)ws; ws += (size_t)4096 * 4096 * 2;  // [4096][4096]
  ushort* vt    = (ushort*)ws; ws += (size_t)4096 * 2048 * 2;  // [(b,h,d)][2048]
  ushort* aout  = (ushort*)ws; ws += (size_t)4096 * 2048 * 2;  // [4096][2048]

  dim3 tb(32, 8), tg(64, 64);
  k_transpose<<<tg, tb, 0, stream>>>(Wq, WqkvT);
  k_transpose<<<tg, tb, 0, stream>>>(Wk, WqkvT + (size_t)2048 * 2048);
  k_transpose<<<tg, tb, 0, stream>>>(Wv, WqkvT + (size_t)4096 * 2048);
  k_transpose<<<tg, tb, 0, stream>>>(Wo, WoT);

  k_rmsnorm<<<4096, 256, 0, stream>>>(x, rms_w, xn);

  // QKV: M=4096, N=6144, K=2048 -> 768 blocks (3 full CU rounds)
  k_gemm3<0><<<768, 512, 0, stream>>>(xn, WqkvT, qkbuf, vt, nullptr, nullptr);

  // attention: 512 blocks (16 q-blocks x 32 bh), XCD-grouped
  k_attn2<<<512, 256, 0, stream>>>(qkbuf, vt, aout);

  // out = attn @ Wo + x : M=4096, N=2048, K=2048 -> 256 blocks (1 round)
  k_gemm3<1><<<256, 512, 0, stream>>>(aout, WoT, nullptr, nullptr, out, x);
}